// Round 2
// baseline (3014.891 us; speedup 1.0000x reference)
//
#include <hip/hip_runtime.h>

constexpr int NN = 100000;
constexpr int NE = 3200000;
constexpr int DD = 128;
constexpr int NB = 782;          // ceil(NN/128) buckets of 128 nodes
constexpr int RND = 16384;       // edges binned per block
#define BN_EPS 1e-5f

// ---- workspace layout (bytes) ----
constexpr size_t WS_CNT   = 0;            // int[NB]
constexpr size_t WS_COFF  = 4096;         // int[NB+1]
constexpr size_t WS_CUR   = 8192;         // int[NB]
constexpr size_t WS_FLAG  = 12288;        // int[1]
constexpr size_t WS_BNSUM = 12800;        // float[128]
constexpr size_t WS_BNSQ  = 13312;        // float[128]
constexpr size_t WS_ZERO  = 16384;        // memset range
constexpr size_t WS_BIN   = 65536;        // uint[NE] packed (src<<7)|dstlow

// Detect whether edge_index arrived as int64 (odd int32 words all zero).
__global__ void k_detect(const int* __restrict__ ei, int* __restrict__ flag) {
    int lane = threadIdx.x;
    int v = ei[2 * lane + 1];
    unsigned long long b = __ballot(v == 0);
    if (lane == 0) *flag = (b == ~0ull) ? 1 : 0;
}

// Coarse bucket histogram (782 buckets) via block-LDS hist + one flush.
__global__ __launch_bounds__(256) void k_bcount(const int* __restrict__ ei,
                                                const int* __restrict__ flag,
                                                int* __restrict__ cnt) {
    __shared__ int hist[NB];
    for (int i = threadIdx.x; i < NB; i += 256) hist[i] = 0;
    __syncthreads();
    int i64 = *flag;
    int stride = gridDim.x * 256;
    for (int e = blockIdx.x * 256 + threadIdx.x; e < NE; e += stride) {
        int dst = i64 ? ei[2 * (NE + e)] : ei[NE + e];
        atomicAdd(&hist[dst >> 7], 1);
    }
    __syncthreads();
    for (int i = threadIdx.x; i < NB; i += 256) {
        int c = hist[i];
        if (c) atomicAdd(&cnt[i], c);
    }
}

// Exclusive scan of the 782 bucket counts (parallel load, serial scan in LDS).
__global__ __launch_bounds__(256) void k_scan(const int* __restrict__ cnt,
                                              int* __restrict__ coff,
                                              int* __restrict__ cur) {
    __shared__ int s[NB];
    for (int i = threadIdx.x; i < NB; i += 256) s[i] = cnt[i];
    __syncthreads();
    if (threadIdx.x == 0) {
        int acc = 0;
        for (int i = 0; i < NB; ++i) { int c = s[i]; s[i] = acc; acc += c; }
    }
    __syncthreads();
    for (int i = threadIdx.x; i < NB; i += 256) { coff[i] = s[i]; cur[i] = s[i]; }
    if (threadIdx.x == 0) coff[NB] = NE;
}

// Bin edges by coarse bucket with per-block batched cursor reservation so
// writes land in ~20-entry contiguous runs (kills the 16x write amplification).
__global__ __launch_bounds__(256) void k_bin(const int* __restrict__ ei,
                                             const int* __restrict__ flag,
                                             int* __restrict__ cur,
                                             unsigned* __restrict__ bin) {
    __shared__ int hist[NB];
    __shared__ int base[NB];
    __shared__ int rk[NB];
    int tid = threadIdx.x;
    for (int i = tid; i < NB; i += 256) { hist[i] = 0; rk[i] = 0; }
    __syncthreads();
    int i64 = *flag;
    int e0 = blockIdx.x * RND;
    // phase 1: local histogram
    for (int j = tid; j < RND; j += 256) {
        int e = e0 + j;
        if (e < NE) {
            int dst = i64 ? ei[2 * (NE + e)] : ei[NE + e];
            atomicAdd(&hist[dst >> 7], 1);
        }
    }
    __syncthreads();
    // phase 2: one global reservation per non-empty bucket
    for (int b = tid; b < NB; b += 256) {
        int c = hist[b];
        if (c > 0) base[b] = atomicAdd(&cur[b], c);
    }
    __syncthreads();
    // phase 3: ranked placement (re-read edges; L2-hot)
    for (int j = tid; j < RND; j += 256) {
        int e = e0 + j;
        if (e < NE) {
            int src = i64 ? ei[2 * e] : ei[e];
            int dst = i64 ? ei[2 * (NE + e)] : ei[NE + e];
            int b = dst >> 7;
            int r = atomicAdd(&rk[b], 1);
            bin[base[b] + r] = ((unsigned)src << 7) | (unsigned)(dst & 127);
        }
    }
}

// Fused gather + scatter-mean: one block per 128-node bucket. acc in LDS,
// wave-per-edge float2 gather of x[src], ds_add_f32 accumulate, in-LDS degree.
__global__ __launch_bounds__(256) void k_fused(const float* __restrict__ x,
                                               const unsigned* __restrict__ bin,
                                               const int* __restrict__ coff,
                                               float* __restrict__ agg) {
    __shared__ float acc[128][128];   // 64 KB
    __shared__ int degl[128];
    int tid = threadIdx.x;
    float4* a4 = (float4*)&acc[0][0];
    float4 z; z.x = z.y = z.z = z.w = 0.f;
    for (int i = tid; i < 128 * 128 / 4; i += 256) a4[i] = z;
    if (tid < 128) degl[tid] = 0;
    __syncthreads();

    int e0 = coff[blockIdx.x];
    int e1 = coff[blockIdx.x + 1];
    int cntE = e1 - e0;
    int wid = tid >> 6, lane = tid & 63;
    int we0 = e0 + (cntE * wid) / 4;
    int we1 = e0 + (cntE * (wid + 1)) / 4;
    const float2* x2 = (const float2*)x;

    int j = we0;
    for (; j + 4 <= we1; j += 4) {
        unsigned p0 = bin[j], p1 = bin[j + 1], p2 = bin[j + 2], p3 = bin[j + 3];
        float2 v0 = x2[(size_t)(p0 >> 7) * 64 + lane];
        float2 v1 = x2[(size_t)(p1 >> 7) * 64 + lane];
        float2 v2 = x2[(size_t)(p2 >> 7) * 64 + lane];
        float2 v3 = x2[(size_t)(p3 >> 7) * 64 + lane];
        int d0 = p0 & 127, d1 = p1 & 127, d2 = p2 & 127, d3 = p3 & 127;
        atomicAdd(&acc[d0][2 * lane], v0.x); atomicAdd(&acc[d0][2 * lane + 1], v0.y);
        atomicAdd(&acc[d1][2 * lane], v1.x); atomicAdd(&acc[d1][2 * lane + 1], v1.y);
        atomicAdd(&acc[d2][2 * lane], v2.x); atomicAdd(&acc[d2][2 * lane + 1], v2.y);
        atomicAdd(&acc[d3][2 * lane], v3.x); atomicAdd(&acc[d3][2 * lane + 1], v3.y);
        if (lane == 0) {
            atomicAdd(&degl[d0], 1); atomicAdd(&degl[d1], 1);
            atomicAdd(&degl[d2], 1); atomicAdd(&degl[d3], 1);
        }
    }
    for (; j < we1; ++j) {
        unsigned p = bin[j];
        float2 v = x2[(size_t)(p >> 7) * 64 + lane];
        int d = p & 127;
        atomicAdd(&acc[d][2 * lane], v.x); atomicAdd(&acc[d][2 * lane + 1], v.y);
        if (lane == 0) atomicAdd(&degl[d], 1);
    }
    __syncthreads();

    int nodebase = blockIdx.x * 128;
    for (int i = tid; i < 128 * 32; i += 256) {
        int r = i >> 5;
        int n = nodebase + r;
        if (n < NN) {
            int c4 = i & 31;
            float inv = 1.0f / fmaxf((float)degl[r], 1.0f);
            float4 v = *(float4*)&acc[r][c4 * 4];
            v.x *= inv; v.y *= inv; v.z *= inv; v.w *= inv;
            ((float4*)agg)[(size_t)n * 32 + c4] = v;
        }
    }
}

// x_raw = agg @ W_l + b_l + x @ W_r.  Block: 256 threads -> 32 rows x 128 cols.
__global__ __launch_bounds__(256) void k_gemm(const float* __restrict__ agg,
                                              const float* __restrict__ x,
                                              const float* __restrict__ Wl,
                                              const float* __restrict__ Wr,
                                              const float* __restrict__ bl,
                                              float* __restrict__ out_raw) {
    extern __shared__ float sW[];  // 128*128 floats = 64KB
    int tid = threadIdx.x;
    int cg = tid & 31;
    int rg = tid >> 5;
    int c0 = cg * 4;
    int row0 = blockIdx.x * 32 + rg * 4;

    float acc[4][4] = {};

    #pragma unroll
    for (int m = 0; m < 2; ++m) {
        const float* Wsrc = (m == 0) ? Wl : Wr;
        const float* src  = (m == 0) ? agg : x;
        __syncthreads();
        {
            const float4* W4 = (const float4*)Wsrc;
            float4* sW4 = (float4*)sW;
            for (int i = tid; i < DD * DD / 4; i += 256) sW4[i] = W4[i];
        }
        __syncthreads();
        for (int k = 0; k < DD; k += 4) {
            float w[4][4];
            #pragma unroll
            for (int kk = 0; kk < 4; ++kk) {
                float4 t = *(const float4*)&sW[(k + kk) * DD + c0];
                w[kk][0] = t.x; w[kk][1] = t.y; w[kk][2] = t.z; w[kk][3] = t.w;
            }
            #pragma unroll
            for (int r = 0; r < 4; ++r) {
                float4 t = *(const float4*)&src[(size_t)(row0 + r) * DD + k];
                float a0 = t.x, a1 = t.y, a2 = t.z, a3 = t.w;
                #pragma unroll
                for (int c = 0; c < 4; ++c)
                    acc[r][c] += a0 * w[0][c] + a1 * w[1][c] + a2 * w[2][c] + a3 * w[3][c];
            }
        }
    }

    float4 b4 = *(const float4*)&bl[c0];
    #pragma unroll
    for (int r = 0; r < 4; ++r) {
        float4 o;
        o.x = acc[r][0] + b4.x;
        o.y = acc[r][1] + b4.y;
        o.z = acc[r][2] + b4.z;
        o.w = acc[r][3] + b4.w;
        *(float4*)&out_raw[(size_t)(row0 + r) * DD + c0] = o;
    }
}

__global__ __launch_bounds__(256) void k_stats(const float* __restrict__ raw,
                                               float* __restrict__ bn_sum,
                                               float* __restrict__ bn_sq) {
    __shared__ float s_s[8][128];
    __shared__ float s_q[8][128];
    int cg = threadIdx.x & 31;
    int rg = threadIdx.x >> 5;
    int c0 = cg * 4;
    float s0 = 0, s1 = 0, s2 = 0, s3 = 0;
    float q0 = 0, q1 = 0, q2 = 0, q3 = 0;
    for (int r = blockIdx.x * 8 + rg; r < NN; r += gridDim.x * 8) {
        float4 v = *(const float4*)&raw[(size_t)r * DD + c0];
        s0 += v.x; q0 += v.x * v.x;
        s1 += v.y; q1 += v.y * v.y;
        s2 += v.z; q2 += v.z * v.z;
        s3 += v.w; q3 += v.w * v.w;
    }
    s_s[rg][c0 + 0] = s0; s_s[rg][c0 + 1] = s1; s_s[rg][c0 + 2] = s2; s_s[rg][c0 + 3] = s3;
    s_q[rg][c0 + 0] = q0; s_q[rg][c0 + 1] = q1; s_q[rg][c0 + 2] = q2; s_q[rg][c0 + 3] = q3;
    __syncthreads();
    if (threadIdx.x < 128) {
        float ts = 0, tq = 0;
        #pragma unroll
        for (int g = 0; g < 8; ++g) {
            ts += s_s[g][threadIdx.x];
            tq += s_q[g][threadIdx.x];
        }
        atomicAdd(&bn_sum[threadIdx.x], ts);
        atomicAdd(&bn_sq[threadIdx.x], tq);
    }
}

__global__ __launch_bounds__(256) void k_norm(const float* __restrict__ raw,
                                              const float* __restrict__ bn_sum,
                                              const float* __restrict__ bn_sq,
                                              const float* __restrict__ gamma,
                                              const float* __restrict__ beta,
                                              float* __restrict__ out) {
    const float invN = 1.0f / (float)NN;
    int total = NN * DD / 4;
    for (int idx = blockIdx.x * 256 + threadIdx.x; idx < total; idx += gridDim.x * 256) {
        int cp = idx & 31;
        float4 v = ((const float4*)raw)[idx];
        float4 s = ((const float4*)bn_sum)[cp];
        float4 q = ((const float4*)bn_sq)[cp];
        float4 g = ((const float4*)gamma)[cp];
        float4 b = ((const float4*)beta)[cp];
        float4 o;
        { float mu = s.x * invN; float var = q.x * invN - mu * mu;
          o.x = (v.x - mu) * rsqrtf(var + BN_EPS) * g.x + b.x; }
        { float mu = s.y * invN; float var = q.y * invN - mu * mu;
          o.y = (v.y - mu) * rsqrtf(var + BN_EPS) * g.y + b.y; }
        { float mu = s.z * invN; float var = q.z * invN - mu * mu;
          o.z = (v.z - mu) * rsqrtf(var + BN_EPS) * g.z + b.z; }
        { float mu = s.w * invN; float var = q.w * invN - mu * mu;
          o.w = (v.w - mu) * rsqrtf(var + BN_EPS) * g.w + b.w; }
        ((float4*)out)[idx] = o;
    }
}

extern "C" void kernel_launch(void* const* d_in, const int* in_sizes, int n_in,
                              void* d_out, int out_size, void* d_ws, size_t ws_size,
                              hipStream_t stream) {
    const float* x     = (const float*)d_in[0];
    const int*   ei    = (const int*)d_in[1];
    const float* Wl    = (const float*)d_in[2];
    const float* bl    = (const float*)d_in[3];
    const float* Wr    = (const float*)d_in[4];
    const float* gamma = (const float*)d_in[5];
    const float* beta  = (const float*)d_in[6];

    float* out_raw = (float*)d_out;                 // [NN][DD] x_raw
    float* out_bn  = out_raw + (size_t)NN * DD;     // [NN][DD] x_deskewed (temp agg)

    char* ws = (char*)d_ws;
    int*      cnt    = (int*)(ws + WS_CNT);
    int*      coff   = (int*)(ws + WS_COFF);
    int*      cur    = (int*)(ws + WS_CUR);
    int*      flag   = (int*)(ws + WS_FLAG);
    float*    bn_sum = (float*)(ws + WS_BNSUM);
    float*    bn_sq  = (float*)(ws + WS_BNSQ);
    unsigned* bin    = (unsigned*)(ws + WS_BIN);

    hipMemsetAsync(d_ws, 0, WS_ZERO, stream);

    k_detect<<<1, 64, 0, stream>>>(ei, flag);
    k_bcount<<<256, 256, 0, stream>>>(ei, flag, cnt);
    k_scan<<<1, 256, 0, stream>>>(cnt, coff, cur);
    k_bin<<<(NE + RND - 1) / RND, 256, 0, stream>>>(ei, flag, cur, bin);
    k_fused<<<NB, 256, 0, stream>>>(x, bin, coff, out_bn);
    k_gemm<<<NN / 32, 256, DD * DD * sizeof(float), stream>>>(out_bn, x, Wl, Wr, bl, out_raw);
    k_stats<<<512, 256, 0, stream>>>(out_raw, bn_sum, bn_sq);
    k_norm<<<4096, 256, 0, stream>>>(out_raw, bn_sum, bn_sq, gamma, beta, out_bn);
}

// Round 3
// 570.019 us; speedup vs baseline: 5.2891x; 5.2891x over previous
//
#include <hip/hip_runtime.h>

constexpr int NN = 100000;
constexpr int NE = 3200000;
constexpr int DD = 128;
constexpr int NB = 782;          // ceil(NN/128) buckets of 128 nodes
constexpr int RND = 16384;       // edges binned per block
#define BN_EPS 1e-5f

// ---- workspace layout (bytes) ----
constexpr size_t WS_CNT   = 0;            // int[NB]
constexpr size_t WS_COFF  = 4096;         // int[NB+1]
constexpr size_t WS_CUR   = 8192;         // int[NB]
constexpr size_t WS_FLAG  = 12288;        // int[1]
constexpr size_t WS_BNSUM = 12800;        // float[128]
constexpr size_t WS_BNSQ  = 13312;        // float[128]
constexpr size_t WS_ZERO  = 16384;        // memset range
constexpr size_t WS_DEG   = 16384;        // int[NN]
constexpr size_t WS_OFF   = 416384;       // int[NN]
constexpr size_t WS_CSR   = 816384;       // int[NE]
// bin[] (uint[NE]) lives in d_out's first half (dead until k_gemm writes it)

// Detect whether edge_index arrived as int64 (odd int32 words all zero).
__global__ void k_detect(const int* __restrict__ ei, int* __restrict__ flag) {
    int lane = threadIdx.x;
    int v = ei[2 * lane + 1];
    unsigned long long b = __ballot(v == 0);
    if (lane == 0) *flag = (b == ~0ull) ? 1 : 0;
}

// Coarse bucket histogram (782 buckets) via block-LDS hist + one flush.
__global__ __launch_bounds__(256) void k_bcount(const int* __restrict__ ei,
                                                const int* __restrict__ flag,
                                                int* __restrict__ cnt) {
    __shared__ int hist[NB];
    for (int i = threadIdx.x; i < NB; i += 256) hist[i] = 0;
    __syncthreads();
    int i64 = *flag;
    int stride = gridDim.x * 256;
    for (int e = blockIdx.x * 256 + threadIdx.x; e < NE; e += stride) {
        int dst = i64 ? ei[2 * (NE + e)] : ei[NE + e];
        atomicAdd(&hist[dst >> 7], 1);
    }
    __syncthreads();
    for (int i = threadIdx.x; i < NB; i += 256) {
        int c = hist[i];
        if (c) atomicAdd(&cnt[i], c);
    }
}

// Exclusive scan of the 782 bucket counts.
__global__ __launch_bounds__(256) void k_scan(const int* __restrict__ cnt,
                                              int* __restrict__ coff,
                                              int* __restrict__ cur) {
    __shared__ int s[NB];
    for (int i = threadIdx.x; i < NB; i += 256) s[i] = cnt[i];
    __syncthreads();
    if (threadIdx.x == 0) {
        int acc = 0;
        for (int i = 0; i < NB; ++i) { int c = s[i]; s[i] = acc; acc += c; }
    }
    __syncthreads();
    for (int i = threadIdx.x; i < NB; i += 256) { coff[i] = s[i]; cur[i] = s[i]; }
    if (threadIdx.x == 0) coff[NB] = NE;
}

// Bin edges by coarse bucket with per-block batched cursor reservation so
// writes land in ~20-entry contiguous runs (kills 16x write amplification).
__global__ __launch_bounds__(256) void k_bin(const int* __restrict__ ei,
                                             const int* __restrict__ flag,
                                             int* __restrict__ cur,
                                             unsigned* __restrict__ bin) {
    __shared__ int hist[NB];
    __shared__ int base[NB];
    __shared__ int rk[NB];
    int tid = threadIdx.x;
    for (int i = tid; i < NB; i += 256) { hist[i] = 0; rk[i] = 0; }
    __syncthreads();
    int i64 = *flag;
    int e0 = blockIdx.x * RND;
    for (int j = tid; j < RND; j += 256) {
        int e = e0 + j;
        if (e < NE) {
            int dst = i64 ? ei[2 * (NE + e)] : ei[NE + e];
            atomicAdd(&hist[dst >> 7], 1);
        }
    }
    __syncthreads();
    for (int b = tid; b < NB; b += 256) {
        int c = hist[b];
        if (c > 0) base[b] = atomicAdd(&cur[b], c);
    }
    __syncthreads();
    for (int j = tid; j < RND; j += 256) {
        int e = e0 + j;
        if (e < NE) {
            int src = i64 ? ei[2 * e] : ei[e];
            int dst = i64 ? ei[2 * (NE + e)] : ei[NE + e];
            int b = dst >> 7;
            int r = atomicAdd(&rk[b], 1);
            bin[base[b] + r] = ((unsigned)src << 7) | (unsigned)(dst & 127);
        }
    }
}

// Per-bucket counting sort: one block per bucket, 128-entry LDS hist + scan,
// emits node-grouped CSR (src ids) + per-node deg/off. Writes stay inside the
// bucket's contiguous 16KB window -> lines fully dirtied, no amplification.
__global__ __launch_bounds__(256) void k_csr(const unsigned* __restrict__ bin,
                                             const int* __restrict__ coff,
                                             int* __restrict__ csr,
                                             int* __restrict__ deg,
                                             int* __restrict__ off) {
    __shared__ int hist[128];
    __shared__ int sb[128];
    __shared__ int curs[128];
    int b = blockIdx.x;
    int tid = threadIdx.x;
    if (tid < 128) hist[tid] = 0;
    __syncthreads();
    int e0 = coff[b], e1 = coff[b + 1];
    for (int j = e0 + tid; j < e1; j += 256)
        atomicAdd(&hist[bin[j] & 127], 1);
    __syncthreads();
    if (tid == 0) {
        int acc = 0;
        for (int i = 0; i < 128; ++i) { sb[i] = acc; acc += hist[i]; }
    }
    __syncthreads();
    if (tid < 128) curs[tid] = sb[tid];
    __syncthreads();
    for (int j = e0 + tid; j < e1; j += 256) {
        unsigned p = bin[j];
        int d = p & 127;
        int r = atomicAdd(&curs[d], 1);
        csr[e0 + r] = (int)(p >> 7);
    }
    int n = b * 128 + tid;
    if (tid < 128 && n < NN) {
        deg[n] = hist[tid];
        off[n] = e0 + sb[tid];
    }
}

// Wave-per-node gather-sum (100K independent waves, no atomics), 4x unrolled.
__global__ __launch_bounds__(256) void k_agg(const float* __restrict__ x,
                                             const int* __restrict__ csr,
                                             const int* __restrict__ deg,
                                             const int* __restrict__ off,
                                             float* __restrict__ agg) {
    int w = (blockIdx.x * 256 + threadIdx.x) >> 6;
    int lane = threadIdx.x & 63;
    if (w >= NN) return;
    int dg = deg[w];
    int o = off[w];
    const float2* x2 = (const float2*)x;
    float ax = 0.f, ay = 0.f;
    int j = 0;
    for (; j + 4 <= dg; j += 4) {
        int s0 = csr[o + j];
        int s1 = csr[o + j + 1];
        int s2 = csr[o + j + 2];
        int s3 = csr[o + j + 3];
        float2 v0 = x2[(size_t)s0 * 64 + lane];
        float2 v1 = x2[(size_t)s1 * 64 + lane];
        float2 v2 = x2[(size_t)s2 * 64 + lane];
        float2 v3 = x2[(size_t)s3 * 64 + lane];
        ax += (v0.x + v1.x) + (v2.x + v3.x);
        ay += (v0.y + v1.y) + (v2.y + v3.y);
    }
    for (; j < dg; ++j) {
        int s = csr[o + j];
        float2 v = x2[(size_t)s * 64 + lane];
        ax += v.x;
        ay += v.y;
    }
    float inv = 1.0f / fmaxf((float)dg, 1.0f);
    float2 r;
    r.x = ax * inv;
    r.y = ay * inv;
    ((float2*)agg)[(size_t)w * 64 + lane] = r;
}

// x_raw = agg @ W_l + b_l + x @ W_r.  Block: 256 threads -> 32 rows x 128 cols.
__global__ __launch_bounds__(256) void k_gemm(const float* __restrict__ agg,
                                              const float* __restrict__ x,
                                              const float* __restrict__ Wl,
                                              const float* __restrict__ Wr,
                                              const float* __restrict__ bl,
                                              float* __restrict__ out_raw) {
    extern __shared__ float sW[];  // 128*128 floats = 64KB
    int tid = threadIdx.x;
    int cg = tid & 31;
    int rg = tid >> 5;
    int c0 = cg * 4;
    int row0 = blockIdx.x * 32 + rg * 4;

    float acc[4][4] = {};

    #pragma unroll
    for (int m = 0; m < 2; ++m) {
        const float* Wsrc = (m == 0) ? Wl : Wr;
        const float* src  = (m == 0) ? agg : x;
        __syncthreads();
        {
            const float4* W4 = (const float4*)Wsrc;
            float4* sW4 = (float4*)sW;
            for (int i = tid; i < DD * DD / 4; i += 256) sW4[i] = W4[i];
        }
        __syncthreads();
        for (int k = 0; k < DD; k += 4) {
            float w[4][4];
            #pragma unroll
            for (int kk = 0; kk < 4; ++kk) {
                float4 t = *(const float4*)&sW[(k + kk) * DD + c0];
                w[kk][0] = t.x; w[kk][1] = t.y; w[kk][2] = t.z; w[kk][3] = t.w;
            }
            #pragma unroll
            for (int r = 0; r < 4; ++r) {
                float4 t = *(const float4*)&src[(size_t)(row0 + r) * DD + k];
                float a0 = t.x, a1 = t.y, a2 = t.z, a3 = t.w;
                #pragma unroll
                for (int c = 0; c < 4; ++c)
                    acc[r][c] += a0 * w[0][c] + a1 * w[1][c] + a2 * w[2][c] + a3 * w[3][c];
            }
        }
    }

    float4 b4 = *(const float4*)&bl[c0];
    #pragma unroll
    for (int r = 0; r < 4; ++r) {
        float4 o;
        o.x = acc[r][0] + b4.x;
        o.y = acc[r][1] + b4.y;
        o.z = acc[r][2] + b4.z;
        o.w = acc[r][3] + b4.w;
        *(float4*)&out_raw[(size_t)(row0 + r) * DD + c0] = o;
    }
}

__global__ __launch_bounds__(256) void k_stats(const float* __restrict__ raw,
                                               float* __restrict__ bn_sum,
                                               float* __restrict__ bn_sq) {
    __shared__ float s_s[8][128];
    __shared__ float s_q[8][128];
    int cg = threadIdx.x & 31;
    int rg = threadIdx.x >> 5;
    int c0 = cg * 4;
    float s0 = 0, s1 = 0, s2 = 0, s3 = 0;
    float q0 = 0, q1 = 0, q2 = 0, q3 = 0;
    for (int r = blockIdx.x * 8 + rg; r < NN; r += gridDim.x * 8) {
        float4 v = *(const float4*)&raw[(size_t)r * DD + c0];
        s0 += v.x; q0 += v.x * v.x;
        s1 += v.y; q1 += v.y * v.y;
        s2 += v.z; q2 += v.z * v.z;
        s3 += v.w; q3 += v.w * v.w;
    }
    s_s[rg][c0 + 0] = s0; s_s[rg][c0 + 1] = s1; s_s[rg][c0 + 2] = s2; s_s[rg][c0 + 3] = s3;
    s_q[rg][c0 + 0] = q0; s_q[rg][c0 + 1] = q1; s_q[rg][c0 + 2] = q2; s_q[rg][c0 + 3] = q3;
    __syncthreads();
    if (threadIdx.x < 128) {
        float ts = 0, tq = 0;
        #pragma unroll
        for (int g = 0; g < 8; ++g) {
            ts += s_s[g][threadIdx.x];
            tq += s_q[g][threadIdx.x];
        }
        atomicAdd(&bn_sum[threadIdx.x], ts);
        atomicAdd(&bn_sq[threadIdx.x], tq);
    }
}

__global__ __launch_bounds__(256) void k_norm(const float* __restrict__ raw,
                                              const float* __restrict__ bn_sum,
                                              const float* __restrict__ bn_sq,
                                              const float* __restrict__ gamma,
                                              const float* __restrict__ beta,
                                              float* __restrict__ out) {
    const float invN = 1.0f / (float)NN;
    int total = NN * DD / 4;
    for (int idx = blockIdx.x * 256 + threadIdx.x; idx < total; idx += gridDim.x * 256) {
        int cp = idx & 31;
        float4 v = ((const float4*)raw)[idx];
        float4 s = ((const float4*)bn_sum)[cp];
        float4 q = ((const float4*)bn_sq)[cp];
        float4 g = ((const float4*)gamma)[cp];
        float4 b = ((const float4*)beta)[cp];
        float4 o;
        { float mu = s.x * invN; float var = q.x * invN - mu * mu;
          o.x = (v.x - mu) * rsqrtf(var + BN_EPS) * g.x + b.x; }
        { float mu = s.y * invN; float var = q.y * invN - mu * mu;
          o.y = (v.y - mu) * rsqrtf(var + BN_EPS) * g.y + b.y; }
        { float mu = s.z * invN; float var = q.z * invN - mu * mu;
          o.z = (v.z - mu) * rsqrtf(var + BN_EPS) * g.z + b.z; }
        { float mu = s.w * invN; float var = q.w * invN - mu * mu;
          o.w = (v.w - mu) * rsqrtf(var + BN_EPS) * g.w + b.w; }
        ((float4*)out)[idx] = o;
    }
}

extern "C" void kernel_launch(void* const* d_in, const int* in_sizes, int n_in,
                              void* d_out, int out_size, void* d_ws, size_t ws_size,
                              hipStream_t stream) {
    const float* x     = (const float*)d_in[0];
    const int*   ei    = (const int*)d_in[1];
    const float* Wl    = (const float*)d_in[2];
    const float* bl    = (const float*)d_in[3];
    const float* Wr    = (const float*)d_in[4];
    const float* gamma = (const float*)d_in[5];
    const float* beta  = (const float*)d_in[6];

    float* out_raw = (float*)d_out;                 // [NN][DD] x_raw
    float* out_bn  = out_raw + (size_t)NN * DD;     // [NN][DD] x_deskewed (temp agg)
    unsigned* bin  = (unsigned*)d_out;              // uint[NE], dead before k_gemm writes

    char* ws = (char*)d_ws;
    int*   cnt    = (int*)(ws + WS_CNT);
    int*   coff   = (int*)(ws + WS_COFF);
    int*   cur    = (int*)(ws + WS_CUR);
    int*   flag   = (int*)(ws + WS_FLAG);
    float* bn_sum = (float*)(ws + WS_BNSUM);
    float* bn_sq  = (float*)(ws + WS_BNSQ);
    int*   deg    = (int*)(ws + WS_DEG);
    int*   off    = (int*)(ws + WS_OFF);
    int*   csr    = (int*)(ws + WS_CSR);

    hipMemsetAsync(d_ws, 0, WS_ZERO, stream);

    k_detect<<<1, 64, 0, stream>>>(ei, flag);
    k_bcount<<<256, 256, 0, stream>>>(ei, flag, cnt);
    k_scan<<<1, 256, 0, stream>>>(cnt, coff, cur);
    k_bin<<<(NE + RND - 1) / RND, 256, 0, stream>>>(ei, flag, cur, bin);
    k_csr<<<NB, 256, 0, stream>>>(bin, coff, csr, deg, off);
    k_agg<<<(NN * 64 + 255) / 256, 256, 0, stream>>>(x, csr, deg, off, out_bn);
    k_gemm<<<NN / 32, 256, DD * DD * sizeof(float), stream>>>(out_bn, x, Wl, Wr, bl, out_raw);
    k_stats<<<512, 256, 0, stream>>>(out_raw, bn_sum, bn_sq);
    k_norm<<<4096, 256, 0, stream>>>(out_raw, bn_sum, bn_sq, gamma, beta, out_bn);
}

// Round 4
// 504.551 us; speedup vs baseline: 5.9754x; 1.1298x over previous
//
#include <hip/hip_runtime.h>

constexpr int NN = 100000;
constexpr int NE = 3200000;
constexpr int DD = 128;
constexpr int NB = 782;          // ceil(NN/128) buckets of 128 nodes
constexpr int RND = 16384;       // edges binned per block
constexpr int KC = 32;           // W chunk rows staged in LDS (16KB)
#define BN_EPS 1e-5f

// ---- workspace layout (bytes) ----
constexpr size_t WS_CNT   = 0;            // int[NB]
constexpr size_t WS_COFF  = 4096;         // int[NB+1]
constexpr size_t WS_CUR   = 8192;         // int[NB]
constexpr size_t WS_FLAG  = 12288;        // int[1]
constexpr size_t WS_BNSUM = 12800;        // float[128]
constexpr size_t WS_BNSQ  = 13312;        // float[128]
constexpr size_t WS_ZERO  = 16384;        // memset range
constexpr size_t WS_DEG   = 16384;        // int[NN]
constexpr size_t WS_OFF   = 416384;       // int[NN]
constexpr size_t WS_CSR   = 816384;       // int[NE]
// bin[] (uint[NE]) lives in d_out's first half (dead until k_gemm writes it)

// Detect whether edge_index arrived as int64 (odd int32 words all zero).
__global__ void k_detect(const int* __restrict__ ei, int* __restrict__ flag) {
    int lane = threadIdx.x;
    int v = ei[2 * lane + 1];
    unsigned long long b = __ballot(v == 0);
    if (lane == 0) *flag = (b == ~0ull) ? 1 : 0;
}

// Coarse bucket histogram (782 buckets) via block-LDS hist + one flush.
__global__ __launch_bounds__(256) void k_bcount(const int* __restrict__ ei,
                                                const int* __restrict__ flag,
                                                int* __restrict__ cnt) {
    __shared__ int hist[NB];
    for (int i = threadIdx.x; i < NB; i += 256) hist[i] = 0;
    __syncthreads();
    int i64 = *flag;
    int stride = gridDim.x * 256;
    for (int e = blockIdx.x * 256 + threadIdx.x; e < NE; e += stride) {
        int dst = i64 ? ei[2 * (NE + e)] : ei[NE + e];
        atomicAdd(&hist[dst >> 7], 1);
    }
    __syncthreads();
    for (int i = threadIdx.x; i < NB; i += 256) {
        int c = hist[i];
        if (c) atomicAdd(&cnt[i], c);
    }
}

// Exclusive scan of the 782 bucket counts.
__global__ __launch_bounds__(256) void k_scan(const int* __restrict__ cnt,
                                              int* __restrict__ coff,
                                              int* __restrict__ cur) {
    __shared__ int s[NB];
    for (int i = threadIdx.x; i < NB; i += 256) s[i] = cnt[i];
    __syncthreads();
    if (threadIdx.x == 0) {
        int acc = 0;
        for (int i = 0; i < NB; ++i) { int c = s[i]; s[i] = acc; acc += c; }
    }
    __syncthreads();
    for (int i = threadIdx.x; i < NB; i += 256) { coff[i] = s[i]; cur[i] = s[i]; }
    if (threadIdx.x == 0) coff[NB] = NE;
}

// Bin edges by coarse bucket with per-block batched cursor reservation so
// writes land in ~20-entry contiguous runs (kills 16x write amplification).
__global__ __launch_bounds__(256) void k_bin(const int* __restrict__ ei,
                                             const int* __restrict__ flag,
                                             int* __restrict__ cur,
                                             unsigned* __restrict__ bin) {
    __shared__ int hist[NB];
    __shared__ int base[NB];
    __shared__ int rk[NB];
    int tid = threadIdx.x;
    for (int i = tid; i < NB; i += 256) { hist[i] = 0; rk[i] = 0; }
    __syncthreads();
    int i64 = *flag;
    int e0 = blockIdx.x * RND;
    for (int j = tid; j < RND; j += 256) {
        int e = e0 + j;
        if (e < NE) {
            int dst = i64 ? ei[2 * (NE + e)] : ei[NE + e];
            atomicAdd(&hist[dst >> 7], 1);
        }
    }
    __syncthreads();
    for (int b = tid; b < NB; b += 256) {
        int c = hist[b];
        if (c > 0) base[b] = atomicAdd(&cur[b], c);
    }
    __syncthreads();
    for (int j = tid; j < RND; j += 256) {
        int e = e0 + j;
        if (e < NE) {
            int src = i64 ? ei[2 * e] : ei[e];
            int dst = i64 ? ei[2 * (NE + e)] : ei[NE + e];
            int b = dst >> 7;
            int r = atomicAdd(&rk[b], 1);
            bin[base[b] + r] = ((unsigned)src << 7) | (unsigned)(dst & 127);
        }
    }
}

// Per-bucket counting sort: one block per bucket, 128-entry LDS hist + scan,
// emits node-grouped CSR (src ids) + per-node deg/off.
__global__ __launch_bounds__(256) void k_csr(const unsigned* __restrict__ bin,
                                             const int* __restrict__ coff,
                                             int* __restrict__ csr,
                                             int* __restrict__ deg,
                                             int* __restrict__ off) {
    __shared__ int hist[128];
    __shared__ int sb[128];
    __shared__ int curs[128];
    int b = blockIdx.x;
    int tid = threadIdx.x;
    if (tid < 128) hist[tid] = 0;
    __syncthreads();
    int e0 = coff[b], e1 = coff[b + 1];
    for (int j = e0 + tid; j < e1; j += 256)
        atomicAdd(&hist[bin[j] & 127], 1);
    __syncthreads();
    if (tid == 0) {
        int acc = 0;
        for (int i = 0; i < 128; ++i) { sb[i] = acc; acc += hist[i]; }
    }
    __syncthreads();
    if (tid < 128) curs[tid] = sb[tid];
    __syncthreads();
    for (int j = e0 + tid; j < e1; j += 256) {
        unsigned p = bin[j];
        int d = p & 127;
        int r = atomicAdd(&curs[d], 1);
        csr[e0 + r] = (int)(p >> 7);
    }
    int n = b * 128 + tid;
    if (tid < 128 && n < NN) {
        deg[n] = hist[tid];
        off[n] = e0 + sb[tid];
    }
}

// Wave-per-node gather-sum (100K independent waves, no atomics), 4x unrolled.
__global__ __launch_bounds__(256) void k_agg(const float* __restrict__ x,
                                             const int* __restrict__ csr,
                                             const int* __restrict__ deg,
                                             const int* __restrict__ off,
                                             float* __restrict__ agg) {
    int w = (blockIdx.x * 256 + threadIdx.x) >> 6;
    int lane = threadIdx.x & 63;
    if (w >= NN) return;
    int dg = deg[w];
    int o = off[w];
    const float2* x2 = (const float2*)x;
    float ax = 0.f, ay = 0.f;
    int j = 0;
    for (; j + 4 <= dg; j += 4) {
        int s0 = csr[o + j];
        int s1 = csr[o + j + 1];
        int s2 = csr[o + j + 2];
        int s3 = csr[o + j + 3];
        float2 v0 = x2[(size_t)s0 * 64 + lane];
        float2 v1 = x2[(size_t)s1 * 64 + lane];
        float2 v2 = x2[(size_t)s2 * 64 + lane];
        float2 v3 = x2[(size_t)s3 * 64 + lane];
        ax += (v0.x + v1.x) + (v2.x + v3.x);
        ay += (v0.y + v1.y) + (v2.y + v3.y);
    }
    for (; j < dg; ++j) {
        int s = csr[o + j];
        float2 v = x2[(size_t)s * 64 + lane];
        ax += v.x;
        ay += v.y;
    }
    float inv = 1.0f / fmaxf((float)dg, 1.0f);
    float2 r;
    r.x = ax * inv;
    r.y = ay * inv;
    ((float2*)agg)[(size_t)w * 64 + lane] = r;
}

// x_raw = agg @ W_l + b_l + x @ W_r, with BN stats fused into the epilogue.
// Block: 256 threads -> 64 rows x 128 cols; thread: 8 rows x 4 cols.
// W staged in 16KB chunks (32 k-rows) for ~20 waves/CU occupancy.
// Half-wave layout: 32 lanes cover the 128 cols of shared rows (A broadcast).
__global__ __launch_bounds__(256) void k_gemm(const float* __restrict__ agg,
                                              const float* __restrict__ x,
                                              const float* __restrict__ Wl,
                                              const float* __restrict__ Wr,
                                              const float* __restrict__ bl,
                                              float* __restrict__ out_raw,
                                              float* __restrict__ bn_sum,
                                              float* __restrict__ bn_sq) {
    __shared__ float sW[KC][DD];     // 16KB
    int tid = threadIdx.x;
    int cg = tid & 31;
    int rg = tid >> 5;               // 0..7
    int c0 = cg * 4;
    int row0 = blockIdx.x * 64 + rg * 8;

    float acc[8][4] = {};

    #pragma unroll
    for (int m = 0; m < 2; ++m) {
        const float* W = (m == 0) ? Wl : Wr;
        const float* A = (m == 0) ? agg : x;
        for (int kc = 0; kc < DD; kc += KC) {
            __syncthreads();
            {
                const float4* W4 = (const float4*)(W + (size_t)kc * DD);
                float4* s4 = (float4*)&sW[0][0];
                #pragma unroll
                for (int i = 0; i < 4; ++i) s4[tid + 256 * i] = W4[tid + 256 * i];
            }
            __syncthreads();
            for (int k = 0; k < KC; k += 4) {
                float4 a[8];
                #pragma unroll
                for (int r = 0; r < 8; ++r) {
                    int row = row0 + r;
                    if (row >= NN) row = NN - 1;
                    a[r] = *(const float4*)&A[(size_t)row * DD + kc + k];
                }
                #pragma unroll
                for (int kk = 0; kk < 4; ++kk) {
                    float4 w = *(const float4*)&sW[k + kk][c0];
                    #pragma unroll
                    for (int r = 0; r < 8; ++r) {
                        float av = (&a[r].x)[kk];
                        acc[r][0] += av * w.x;
                        acc[r][1] += av * w.y;
                        acc[r][2] += av * w.z;
                        acc[r][3] += av * w.w;
                    }
                }
            }
        }
    }

    // epilogue: bias, store x_raw, per-thread column stats
    float4 b4 = *(const float4*)&bl[c0];
    float s0 = 0, s1 = 0, s2 = 0, s3 = 0;
    float q0 = 0, q1 = 0, q2 = 0, q3 = 0;
    #pragma unroll
    for (int r = 0; r < 8; ++r) {
        int row = row0 + r;
        if (row < NN) {
            float4 o;
            o.x = acc[r][0] + b4.x;
            o.y = acc[r][1] + b4.y;
            o.z = acc[r][2] + b4.z;
            o.w = acc[r][3] + b4.w;
            *(float4*)&out_raw[(size_t)row * DD + c0] = o;
            s0 += o.x; q0 += o.x * o.x;
            s1 += o.y; q1 += o.y * o.y;
            s2 += o.z; q2 += o.z * o.z;
            s3 += o.w; q3 += o.w * o.w;
        }
    }

    // block-level column reduce in LDS (reuse sW: need 2*8*128 floats <= 4096)
    __syncthreads();
    float* sp = &sW[0][0];         // [8][128]
    float* qp = sp + 1024;         // [8][128]
    *(float4*)&sp[rg * 128 + c0] = make_float4(s0, s1, s2, s3);
    *(float4*)&qp[rg * 128 + c0] = make_float4(q0, q1, q2, q3);
    __syncthreads();
    if (tid < 128) {
        float ts = 0, tq = 0;
        #pragma unroll
        for (int g = 0; g < 8; ++g) {
            ts += sp[g * 128 + tid];
            tq += qp[g * 128 + tid];
        }
        atomicAdd(&bn_sum[tid], ts);
        atomicAdd(&bn_sq[tid], tq);
    }
}

__global__ __launch_bounds__(256) void k_norm(const float* __restrict__ raw,
                                              const float* __restrict__ bn_sum,
                                              const float* __restrict__ bn_sq,
                                              const float* __restrict__ gamma,
                                              const float* __restrict__ beta,
                                              float* __restrict__ out) {
    const float invN = 1.0f / (float)NN;
    int total = NN * DD / 4;
    for (int idx = blockIdx.x * 256 + threadIdx.x; idx < total; idx += gridDim.x * 256) {
        int cp = idx & 31;
        float4 v = ((const float4*)raw)[idx];
        float4 s = ((const float4*)bn_sum)[cp];
        float4 q = ((const float4*)bn_sq)[cp];
        float4 g = ((const float4*)gamma)[cp];
        float4 b = ((const float4*)beta)[cp];
        float4 o;
        { float mu = s.x * invN; float var = q.x * invN - mu * mu;
          o.x = (v.x - mu) * rsqrtf(var + BN_EPS) * g.x + b.x; }
        { float mu = s.y * invN; float var = q.y * invN - mu * mu;
          o.y = (v.y - mu) * rsqrtf(var + BN_EPS) * g.y + b.y; }
        { float mu = s.z * invN; float var = q.z * invN - mu * mu;
          o.z = (v.z - mu) * rsqrtf(var + BN_EPS) * g.z + b.z; }
        { float mu = s.w * invN; float var = q.w * invN - mu * mu;
          o.w = (v.w - mu) * rsqrtf(var + BN_EPS) * g.w + b.w; }
        ((float4*)out)[idx] = o;
    }
}

extern "C" void kernel_launch(void* const* d_in, const int* in_sizes, int n_in,
                              void* d_out, int out_size, void* d_ws, size_t ws_size,
                              hipStream_t stream) {
    const float* x     = (const float*)d_in[0];
    const int*   ei    = (const int*)d_in[1];
    const float* Wl    = (const float*)d_in[2];
    const float* bl    = (const float*)d_in[3];
    const float* Wr    = (const float*)d_in[4];
    const float* gamma = (const float*)d_in[5];
    const float* beta  = (const float*)d_in[6];

    float* out_raw = (float*)d_out;                 // [NN][DD] x_raw
    float* out_bn  = out_raw + (size_t)NN * DD;     // [NN][DD] x_deskewed (temp agg)
    unsigned* bin  = (unsigned*)d_out;              // uint[NE], dead before k_gemm writes

    char* ws = (char*)d_ws;
    int*   cnt    = (int*)(ws + WS_CNT);
    int*   coff   = (int*)(ws + WS_COFF);
    int*   cur    = (int*)(ws + WS_CUR);
    int*   flag   = (int*)(ws + WS_FLAG);
    float* bn_sum = (float*)(ws + WS_BNSUM);
    float* bn_sq  = (float*)(ws + WS_BNSQ);
    int*   deg    = (int*)(ws + WS_DEG);
    int*   off    = (int*)(ws + WS_OFF);
    int*   csr    = (int*)(ws + WS_CSR);

    hipMemsetAsync(d_ws, 0, WS_ZERO, stream);

    k_detect<<<1, 64, 0, stream>>>(ei, flag);
    k_bcount<<<256, 256, 0, stream>>>(ei, flag, cnt);
    k_scan<<<1, 256, 0, stream>>>(cnt, coff, cur);
    k_bin<<<(NE + RND - 1) / RND, 256, 0, stream>>>(ei, flag, cur, bin);
    k_csr<<<NB, 256, 0, stream>>>(bin, coff, csr, deg, off);
    k_agg<<<(NN * 64 + 255) / 256, 256, 0, stream>>>(x, csr, deg, off, out_bn);
    k_gemm<<<(NN + 63) / 64, 256, 0, stream>>>(out_bn, x, Wl, Wr, bl, out_raw, bn_sum, bn_sq);
    k_norm<<<4096, 256, 0, stream>>>(out_raw, bn_sum, bn_sq, gamma, beta, out_bn);
}

// Round 5
// 502.180 us; speedup vs baseline: 6.0036x; 1.0047x over previous
//
#include <hip/hip_runtime.h>

constexpr int NN = 100000;
constexpr int NE = 3200000;
constexpr int DD = 128;
constexpr int NB = 782;          // ceil(NN/128) buckets of 128 nodes
constexpr int RND = 8192;        // edges binned per block (391 blocks)
constexpr int KC = 32;           // W chunk rows staged in LDS (16KB)
#define BN_EPS 1e-5f

// ---- workspace layout (bytes) ----
constexpr size_t WS_CNT   = 0;            // int[NB]
constexpr size_t WS_COFF  = 4096;         // int[NB+1]
constexpr size_t WS_CUR   = 8192;         // int[NB]
constexpr size_t WS_FLAG  = 12288;        // int[1]
constexpr size_t WS_BNSUM = 12800;        // float[128]
constexpr size_t WS_BNSQ  = 13312;        // float[128]
constexpr size_t WS_ZERO  = 16384;        // memset range
constexpr size_t WS_DEG   = 16384;        // int[NN]
constexpr size_t WS_OFF   = 416384;       // int[NN]
constexpr size_t WS_CSR   = 816384;       // int[NE]
// bin[] (uint[NE]) lives in d_out's first half (dead until k_gemm writes it)

// Detect whether edge_index arrived as int64 (odd int32 words all zero).
__global__ void k_detect(const int* __restrict__ ei, int* __restrict__ flag) {
    int lane = threadIdx.x;
    int v = ei[2 * lane + 1];
    unsigned long long b = __ballot(v == 0);
    if (lane == 0) *flag = (b == ~0ull) ? 1 : 0;
}

// Coarse bucket histogram (782 buckets) via block-LDS hist + one flush.
__global__ __launch_bounds__(256) void k_bcount(const int* __restrict__ ei,
                                                const int* __restrict__ flag,
                                                int* __restrict__ cnt) {
    __shared__ int hist[NB];
    for (int i = threadIdx.x; i < NB; i += 256) hist[i] = 0;
    __syncthreads();
    int i64 = *flag;
    int stride = gridDim.x * 256;
    for (int e = blockIdx.x * 256 + threadIdx.x; e < NE; e += stride) {
        int dst = i64 ? ei[2 * (NE + e)] : ei[NE + e];
        atomicAdd(&hist[dst >> 7], 1);
    }
    __syncthreads();
    for (int i = threadIdx.x; i < NB; i += 256) {
        int c = hist[i];
        if (c) atomicAdd(&cnt[i], c);
    }
}

// Exclusive scan of the 782 bucket counts.
__global__ __launch_bounds__(256) void k_scan(const int* __restrict__ cnt,
                                              int* __restrict__ coff,
                                              int* __restrict__ cur) {
    __shared__ int s[NB];
    for (int i = threadIdx.x; i < NB; i += 256) s[i] = cnt[i];
    __syncthreads();
    if (threadIdx.x == 0) {
        int acc = 0;
        for (int i = 0; i < NB; ++i) { int c = s[i]; s[i] = acc; acc += c; }
    }
    __syncthreads();
    for (int i = threadIdx.x; i < NB; i += 256) { coff[i] = s[i]; cur[i] = s[i]; }
    if (threadIdx.x == 0) coff[NB] = NE;
}

// Bin edges by coarse bucket with per-block batched cursor reservation so
// writes land in ~10-entry contiguous runs (kills 16x write amplification).
__global__ __launch_bounds__(256) void k_bin(const int* __restrict__ ei,
                                             const int* __restrict__ flag,
                                             int* __restrict__ cur,
                                             unsigned* __restrict__ bin) {
    __shared__ int hist[NB];
    __shared__ int base[NB];
    __shared__ int rk[NB];
    int tid = threadIdx.x;
    for (int i = tid; i < NB; i += 256) { hist[i] = 0; rk[i] = 0; }
    __syncthreads();
    int i64 = *flag;
    int e0 = blockIdx.x * RND;
    for (int j = tid; j < RND; j += 256) {
        int e = e0 + j;
        if (e < NE) {
            int dst = i64 ? ei[2 * (NE + e)] : ei[NE + e];
            atomicAdd(&hist[dst >> 7], 1);
        }
    }
    __syncthreads();
    for (int b = tid; b < NB; b += 256) {
        int c = hist[b];
        if (c > 0) base[b] = atomicAdd(&cur[b], c);
    }
    __syncthreads();
    for (int j = tid; j < RND; j += 256) {
        int e = e0 + j;
        if (e < NE) {
            int src = i64 ? ei[2 * e] : ei[e];
            int dst = i64 ? ei[2 * (NE + e)] : ei[NE + e];
            int b = dst >> 7;
            int r = atomicAdd(&rk[b], 1);
            bin[base[b] + r] = ((unsigned)src << 7) | (unsigned)(dst & 127);
        }
    }
}

// Per-bucket counting sort: one block per bucket, 128-entry LDS hist + scan,
// emits node-grouped CSR (src ids) + per-node deg/off.
__global__ __launch_bounds__(256) void k_csr(const unsigned* __restrict__ bin,
                                             const int* __restrict__ coff,
                                             int* __restrict__ csr,
                                             int* __restrict__ deg,
                                             int* __restrict__ off) {
    __shared__ int hist[128];
    __shared__ int sb[128];
    __shared__ int curs[128];
    int b = blockIdx.x;
    int tid = threadIdx.x;
    if (tid < 128) hist[tid] = 0;
    __syncthreads();
    int e0 = coff[b], e1 = coff[b + 1];
    for (int j = e0 + tid; j < e1; j += 256)
        atomicAdd(&hist[bin[j] & 127], 1);
    __syncthreads();
    if (tid == 0) {
        int acc = 0;
        for (int i = 0; i < 128; ++i) { sb[i] = acc; acc += hist[i]; }
    }
    __syncthreads();
    if (tid < 128) curs[tid] = sb[tid];
    __syncthreads();
    for (int j = e0 + tid; j < e1; j += 256) {
        unsigned p = bin[j];
        int d = p & 127;
        int r = atomicAdd(&curs[d], 1);
        csr[e0 + r] = (int)(p >> 7);
    }
    int n = b * 128 + tid;
    if (tid < 128 && n < NN) {
        deg[n] = hist[tid];
        off[n] = e0 + sb[tid];
    }
}

// Wave-per-node gather-sum. float4/lane, 2 rows per wave-instruction
// (lanes 0-31 = even edge, 32-63 = odd edge), 8 edges per iteration.
// Cross-half combine via 4x shfl_xor(32); zero atomics.
__global__ __launch_bounds__(256) void k_agg(const float* __restrict__ x,
                                             const int* __restrict__ csr,
                                             const int* __restrict__ deg,
                                             const int* __restrict__ off,
                                             float* __restrict__ agg) {
    int w = (blockIdx.x * 256 + threadIdx.x) >> 6;
    int lane = threadIdx.x & 63;
    if (w >= NN) return;
    int dg = deg[w];
    int o = off[w];
    int half = lane >> 5;     // which of the 2 edges this lane loads
    int cl = lane & 31;       // float4 column slot (covers 128 floats)
    const float4* x4 = (const float4*)x;
    float ax = 0.f, ay = 0.f, az = 0.f, aw = 0.f;

    int j = 0;
    for (; j + 8 <= dg; j += 8) {
        int s0 = csr[o + j + 0 + half];
        int s1 = csr[o + j + 2 + half];
        int s2 = csr[o + j + 4 + half];
        int s3 = csr[o + j + 6 + half];
        float4 v0 = x4[(size_t)s0 * 32 + cl];
        float4 v1 = x4[(size_t)s1 * 32 + cl];
        float4 v2 = x4[(size_t)s2 * 32 + cl];
        float4 v3 = x4[(size_t)s3 * 32 + cl];
        ax += (v0.x + v1.x) + (v2.x + v3.x);
        ay += (v0.y + v1.y) + (v2.y + v3.y);
        az += (v0.z + v1.z) + (v2.z + v3.z);
        aw += (v0.w + v1.w) + (v2.w + v3.w);
    }
    for (; j + 2 <= dg; j += 2) {
        int s = csr[o + j + half];
        float4 v = x4[(size_t)s * 32 + cl];
        ax += v.x; ay += v.y; az += v.z; aw += v.w;
    }
    if (j < dg && half == 0) {   // last odd edge: half 0 only (avoid double count)
        int s = csr[o + j];
        float4 v = x4[(size_t)s * 32 + cl];
        ax += v.x; ay += v.y; az += v.z; aw += v.w;
    }

    // combine the two halves (partner lane = lane ^ 32)
    ax += __shfl_xor(ax, 32);
    ay += __shfl_xor(ay, 32);
    az += __shfl_xor(az, 32);
    aw += __shfl_xor(aw, 32);

    if (half == 0) {
        float inv = 1.0f / fmaxf((float)dg, 1.0f);
        float4 r;
        r.x = ax * inv; r.y = ay * inv; r.z = az * inv; r.w = aw * inv;
        ((float4*)agg)[(size_t)w * 32 + cl] = r;
    }
}

// x_raw = agg @ W_l + b_l + x @ W_r, with BN stats fused into the epilogue.
// Block: 256 threads -> 64 rows x 128 cols; thread: 8 rows x 4 cols.
// W staged in 16KB chunks (32 k-rows).
__global__ __launch_bounds__(256) void k_gemm(const float* __restrict__ agg,
                                              const float* __restrict__ x,
                                              const float* __restrict__ Wl,
                                              const float* __restrict__ Wr,
                                              const float* __restrict__ bl,
                                              float* __restrict__ out_raw,
                                              float* __restrict__ bn_sum,
                                              float* __restrict__ bn_sq) {
    __shared__ float sW[KC][DD];     // 16KB
    int tid = threadIdx.x;
    int cg = tid & 31;
    int rg = tid >> 5;               // 0..7
    int c0 = cg * 4;
    int row0 = blockIdx.x * 64 + rg * 8;

    float acc[8][4] = {};

    #pragma unroll
    for (int m = 0; m < 2; ++m) {
        const float* W = (m == 0) ? Wl : Wr;
        const float* A = (m == 0) ? agg : x;
        for (int kc = 0; kc < DD; kc += KC) {
            __syncthreads();
            {
                const float4* W4 = (const float4*)(W + (size_t)kc * DD);
                float4* s4 = (float4*)&sW[0][0];
                #pragma unroll
                for (int i = 0; i < 4; ++i) s4[tid + 256 * i] = W4[tid + 256 * i];
            }
            __syncthreads();
            for (int k = 0; k < KC; k += 4) {
                float4 a[8];
                #pragma unroll
                for (int r = 0; r < 8; ++r) {
                    int row = row0 + r;
                    if (row >= NN) row = NN - 1;
                    a[r] = *(const float4*)&A[(size_t)row * DD + kc + k];
                }
                #pragma unroll
                for (int kk = 0; kk < 4; ++kk) {
                    float4 w = *(const float4*)&sW[k + kk][c0];
                    #pragma unroll
                    for (int r = 0; r < 8; ++r) {
                        float av = (&a[r].x)[kk];
                        acc[r][0] += av * w.x;
                        acc[r][1] += av * w.y;
                        acc[r][2] += av * w.z;
                        acc[r][3] += av * w.w;
                    }
                }
            }
        }
    }

    // epilogue: bias, store x_raw, per-thread column stats
    float4 b4 = *(const float4*)&bl[c0];
    float s0 = 0, s1 = 0, s2 = 0, s3 = 0;
    float q0 = 0, q1 = 0, q2 = 0, q3 = 0;
    #pragma unroll
    for (int r = 0; r < 8; ++r) {
        int row = row0 + r;
        if (row < NN) {
            float4 o;
            o.x = acc[r][0] + b4.x;
            o.y = acc[r][1] + b4.y;
            o.z = acc[r][2] + b4.z;
            o.w = acc[r][3] + b4.w;
            *(float4*)&out_raw[(size_t)row * DD + c0] = o;
            s0 += o.x; q0 += o.x * o.x;
            s1 += o.y; q1 += o.y * o.y;
            s2 += o.z; q2 += o.z * o.z;
            s3 += o.w; q3 += o.w * o.w;
        }
    }

    // block-level column reduce in LDS (reuse sW: 2*8*128 floats <= 4096)
    __syncthreads();
    float* sp = &sW[0][0];         // [8][128]
    float* qp = sp + 1024;         // [8][128]
    *(float4*)&sp[rg * 128 + c0] = make_float4(s0, s1, s2, s3);
    *(float4*)&qp[rg * 128 + c0] = make_float4(q0, q1, q2, q3);
    __syncthreads();
    if (tid < 128) {
        float ts = 0, tq = 0;
        #pragma unroll
        for (int g = 0; g < 8; ++g) {
            ts += sp[g * 128 + tid];
            tq += qp[g * 128 + tid];
        }
        atomicAdd(&bn_sum[tid], ts);
        atomicAdd(&bn_sq[tid], tq);
    }
}

__global__ __launch_bounds__(256) void k_norm(const float* __restrict__ raw,
                                              const float* __restrict__ bn_sum,
                                              const float* __restrict__ bn_sq,
                                              const float* __restrict__ gamma,
                                              const float* __restrict__ beta,
                                              float* __restrict__ out) {
    const float invN = 1.0f / (float)NN;
    int total = NN * DD / 4;
    for (int idx = blockIdx.x * 256 + threadIdx.x; idx < total; idx += gridDim.x * 256) {
        int cp = idx & 31;
        float4 v = ((const float4*)raw)[idx];
        float4 s = ((const float4*)bn_sum)[cp];
        float4 q = ((const float4*)bn_sq)[cp];
        float4 g = ((const float4*)gamma)[cp];
        float4 b = ((const float4*)beta)[cp];
        float4 o;
        { float mu = s.x * invN; float var = q.x * invN - mu * mu;
          o.x = (v.x - mu) * rsqrtf(var + BN_EPS) * g.x + b.x; }
        { float mu = s.y * invN; float var = q.y * invN - mu * mu;
          o.y = (v.y - mu) * rsqrtf(var + BN_EPS) * g.y + b.y; }
        { float mu = s.z * invN; float var = q.z * invN - mu * mu;
          o.z = (v.z - mu) * rsqrtf(var + BN_EPS) * g.z + b.z; }
        { float mu = s.w * invN; float var = q.w * invN - mu * mu;
          o.w = (v.w - mu) * rsqrtf(var + BN_EPS) * g.w + b.w; }
        ((float4*)out)[idx] = o;
    }
}

extern "C" void kernel_launch(void* const* d_in, const int* in_sizes, int n_in,
                              void* d_out, int out_size, void* d_ws, size_t ws_size,
                              hipStream_t stream) {
    const float* x     = (const float*)d_in[0];
    const int*   ei    = (const int*)d_in[1];
    const float* Wl    = (const float*)d_in[2];
    const float* bl    = (const float*)d_in[3];
    const float* Wr    = (const float*)d_in[4];
    const float* gamma = (const float*)d_in[5];
    const float* beta  = (const float*)d_in[6];

    float* out_raw = (float*)d_out;                 // [NN][DD] x_raw
    float* out_bn  = out_raw + (size_t)NN * DD;     // [NN][DD] x_deskewed (temp agg)
    unsigned* bin  = (unsigned*)d_out;              // uint[NE], dead before k_gemm writes

    char* ws = (char*)d_ws;
    int*   cnt    = (int*)(ws + WS_CNT);
    int*   coff   = (int*)(ws + WS_COFF);
    int*   cur    = (int*)(ws + WS_CUR);
    int*   flag   = (int*)(ws + WS_FLAG);
    float* bn_sum = (float*)(ws + WS_BNSUM);
    float* bn_sq  = (float*)(ws + WS_BNSQ);
    int*   deg    = (int*)(ws + WS_DEG);
    int*   off    = (int*)(ws + WS_OFF);
    int*   csr    = (int*)(ws + WS_CSR);

    hipMemsetAsync(d_ws, 0, WS_ZERO, stream);

    k_detect<<<1, 64, 0, stream>>>(ei, flag);
    k_bcount<<<512, 256, 0, stream>>>(ei, flag, cnt);
    k_scan<<<1, 256, 0, stream>>>(cnt, coff, cur);
    k_bin<<<(NE + RND - 1) / RND, 256, 0, stream>>>(ei, flag, cur, bin);
    k_csr<<<NB, 256, 0, stream>>>(bin, coff, csr, deg, off);
    k_agg<<<(NN * 64 + 255) / 256, 256, 0, stream>>>(x, csr, deg, off, out_bn);
    k_gemm<<<(NN + 63) / 64, 256, 0, stream>>>(out_bn, x, Wl, Wr, bl, out_raw, bn_sum, bn_sq);
    k_norm<<<4096, 256, 0, stream>>>(out_raw, bn_sum, bn_sq, gamma, beta, out_bn);
}

// Round 6
// 412.826 us; speedup vs baseline: 7.3031x; 1.2164x over previous
//
#include <hip/hip_runtime.h>

constexpr int NN = 100000;
constexpr int NE = 3200000;
constexpr int DD = 128;
constexpr int NB = 782;          // ceil(NN/128) buckets of 128 nodes
constexpr int RND = 8192;        // edges binned per block (391 blocks)
constexpr int KC = 32;           // W chunk rows staged in LDS (16KB)
#define BN_EPS 1e-5f

// ---- workspace layout (bytes) ----
constexpr size_t WS_CNT   = 0;            // int[NB]
constexpr size_t WS_COFF  = 4096;         // int[NB+1]
constexpr size_t WS_CUR   = 8192;         // int[NB]
constexpr size_t WS_FLAG  = 12288;        // int[1]
constexpr size_t WS_BNSUM = 12800;        // float[128]
constexpr size_t WS_BNSQ  = 13312;        // float[128]
constexpr size_t WS_ZERO  = 16384;        // memset range
constexpr size_t WS_DEG   = 16384;        // int[NN]
constexpr size_t WS_OFF   = 416384;       // int[NN]
constexpr size_t WS_CSR   = 816384;       // int[NE]
// bin[] (uint[NE]) lives in d_out bytes [0, 12.8MB); x_bf16 (uint[NN*64],
// 25.6MB) lives in d_out bytes [12.8MB, 38.4MB) -- both dead before k_gemm
// writes out_raw.

__device__ inline unsigned bf16rne(float f) {
    unsigned u = __float_as_uint(f);
    return (u + 0x7fffu + ((u >> 16) & 1u)) >> 16;
}

// Detect whether edge_index arrived as int64 (odd int32 words all zero).
__global__ void k_detect(const int* __restrict__ ei, int* __restrict__ flag) {
    int lane = threadIdx.x;
    int v = ei[2 * lane + 1];
    unsigned long long b = __ballot(v == 0);
    if (lane == 0) *flag = (b == ~0ull) ? 1 : 0;
}

// Pack x (fp32) into bf16 pairs: xb[i] = (bf16(x[2i+1])<<16) | bf16(x[2i]).
__global__ __launch_bounds__(256) void k_tobf16(const float* __restrict__ x,
                                                unsigned* __restrict__ xb) {
    int total = NN * DD / 4;   // each iteration: 4 floats -> 2 uints
    for (int i = blockIdx.x * 256 + threadIdx.x; i < total; i += gridDim.x * 256) {
        float4 v = ((const float4*)x)[i];
        unsigned a = (bf16rne(v.y) << 16) | bf16rne(v.x);
        unsigned b = (bf16rne(v.w) << 16) | bf16rne(v.z);
        ((uint2*)xb)[i] = make_uint2(a, b);
    }
}

// Coarse bucket histogram (782 buckets) via block-LDS hist + one flush.
__global__ __launch_bounds__(256) void k_bcount(const int* __restrict__ ei,
                                                const int* __restrict__ flag,
                                                int* __restrict__ cnt) {
    __shared__ int hist[NB];
    for (int i = threadIdx.x; i < NB; i += 256) hist[i] = 0;
    __syncthreads();
    int i64 = *flag;
    int stride = gridDim.x * 256;
    for (int e = blockIdx.x * 256 + threadIdx.x; e < NE; e += stride) {
        int dst = i64 ? ei[2 * (NE + e)] : ei[NE + e];
        atomicAdd(&hist[dst >> 7], 1);
    }
    __syncthreads();
    for (int i = threadIdx.x; i < NB; i += 256) {
        int c = hist[i];
        if (c) atomicAdd(&cnt[i], c);
    }
}

// Exclusive scan of the 782 bucket counts.
__global__ __launch_bounds__(256) void k_scan(const int* __restrict__ cnt,
                                              int* __restrict__ coff,
                                              int* __restrict__ cur) {
    __shared__ int s[NB];
    for (int i = threadIdx.x; i < NB; i += 256) s[i] = cnt[i];
    __syncthreads();
    if (threadIdx.x == 0) {
        int acc = 0;
        for (int i = 0; i < NB; ++i) { int c = s[i]; s[i] = acc; acc += c; }
    }
    __syncthreads();
    for (int i = threadIdx.x; i < NB; i += 256) { coff[i] = s[i]; cur[i] = s[i]; }
    if (threadIdx.x == 0) coff[NB] = NE;
}

// Bin edges by coarse bucket with per-block batched cursor reservation so
// writes land in ~10-entry contiguous runs (kills 16x write amplification).
__global__ __launch_bounds__(256) void k_bin(const int* __restrict__ ei,
                                             const int* __restrict__ flag,
                                             int* __restrict__ cur,
                                             unsigned* __restrict__ bin) {
    __shared__ int hist[NB];
    __shared__ int base[NB];
    __shared__ int rk[NB];
    int tid = threadIdx.x;
    for (int i = tid; i < NB; i += 256) { hist[i] = 0; rk[i] = 0; }
    __syncthreads();
    int i64 = *flag;
    int e0 = blockIdx.x * RND;
    for (int j = tid; j < RND; j += 256) {
        int e = e0 + j;
        if (e < NE) {
            int dst = i64 ? ei[2 * (NE + e)] : ei[NE + e];
            atomicAdd(&hist[dst >> 7], 1);
        }
    }
    __syncthreads();
    for (int b = tid; b < NB; b += 256) {
        int c = hist[b];
        if (c > 0) base[b] = atomicAdd(&cur[b], c);
    }
    __syncthreads();
    for (int j = tid; j < RND; j += 256) {
        int e = e0 + j;
        if (e < NE) {
            int src = i64 ? ei[2 * e] : ei[e];
            int dst = i64 ? ei[2 * (NE + e)] : ei[NE + e];
            int b = dst >> 7;
            int r = atomicAdd(&rk[b], 1);
            bin[base[b] + r] = ((unsigned)src << 7) | (unsigned)(dst & 127);
        }
    }
}

// Per-bucket counting sort: one block per bucket, 128-entry LDS hist + scan,
// emits node-grouped CSR (src ids) + per-node deg/off.
__global__ __launch_bounds__(256) void k_csr(const unsigned* __restrict__ bin,
                                             const int* __restrict__ coff,
                                             int* __restrict__ csr,
                                             int* __restrict__ deg,
                                             int* __restrict__ off) {
    __shared__ int hist[128];
    __shared__ int sb[128];
    __shared__ int curs[128];
    int b = blockIdx.x;
    int tid = threadIdx.x;
    if (tid < 128) hist[tid] = 0;
    __syncthreads();
    int e0 = coff[b], e1 = coff[b + 1];
    for (int j = e0 + tid; j < e1; j += 256)
        atomicAdd(&hist[bin[j] & 127], 1);
    __syncthreads();
    if (tid == 0) {
        int acc = 0;
        for (int i = 0; i < 128; ++i) { sb[i] = acc; acc += hist[i]; }
    }
    __syncthreads();
    if (tid < 128) curs[tid] = sb[tid];
    __syncthreads();
    for (int j = e0 + tid; j < e1; j += 256) {
        unsigned p = bin[j];
        int d = p & 127;
        int r = atomicAdd(&curs[d], 1);
        csr[e0 + r] = (int)(p >> 7);
    }
    int n = b * 128 + tid;
    if (tid < 128 && n < NN) {
        deg[n] = hist[tid];
        off[n] = e0 + sb[tid];
    }
}

// Wave-per-node gather-sum from the bf16 copy: one uint (2 bf16) per lane =
// full 256B row per wave-instruction. fp32 accumulate, zero atomics.
__global__ __launch_bounds__(256) void k_agg(const unsigned* __restrict__ xb,
                                             const int* __restrict__ csr,
                                             const int* __restrict__ deg,
                                             const int* __restrict__ off,
                                             float* __restrict__ agg) {
    int w = (blockIdx.x * 256 + threadIdx.x) >> 6;
    int lane = threadIdx.x & 63;
    if (w >= NN) return;
    int dg = deg[w];
    int o = off[w];
    float ax = 0.f, ay = 0.f;
    int j = 0;
    for (; j + 4 <= dg; j += 4) {
        int s0 = csr[o + j];
        int s1 = csr[o + j + 1];
        int s2 = csr[o + j + 2];
        int s3 = csr[o + j + 3];
        unsigned u0 = xb[(size_t)s0 * 64 + lane];
        unsigned u1 = xb[(size_t)s1 * 64 + lane];
        unsigned u2 = xb[(size_t)s2 * 64 + lane];
        unsigned u3 = xb[(size_t)s3 * 64 + lane];
        ax += (__uint_as_float(u0 << 16) + __uint_as_float(u1 << 16)) +
              (__uint_as_float(u2 << 16) + __uint_as_float(u3 << 16));
        ay += (__uint_as_float(u0 & 0xffff0000u) + __uint_as_float(u1 & 0xffff0000u)) +
              (__uint_as_float(u2 & 0xffff0000u) + __uint_as_float(u3 & 0xffff0000u));
    }
    for (; j < dg; ++j) {
        int s = csr[o + j];
        unsigned u = xb[(size_t)s * 64 + lane];
        ax += __uint_as_float(u << 16);
        ay += __uint_as_float(u & 0xffff0000u);
    }
    float inv = 1.0f / fmaxf((float)dg, 1.0f);
    float2 r;
    r.x = ax * inv;   // feature 2*lane
    r.y = ay * inv;   // feature 2*lane+1
    ((float2*)agg)[(size_t)w * 64 + lane] = r;
}

// x_raw = agg @ W_l + b_l + x @ W_r, with BN stats fused into the epilogue.
// Block: 256 threads -> 64 rows x 128 cols; thread: 8 rows x 4 cols.
// W staged in 16KB chunks (32 k-rows).
__global__ __launch_bounds__(256) void k_gemm(const float* __restrict__ agg,
                                              const float* __restrict__ x,
                                              const float* __restrict__ Wl,
                                              const float* __restrict__ Wr,
                                              const float* __restrict__ bl,
                                              float* __restrict__ out_raw,
                                              float* __restrict__ bn_sum,
                                              float* __restrict__ bn_sq) {
    __shared__ float sW[KC][DD];     // 16KB
    int tid = threadIdx.x;
    int cg = tid & 31;
    int rg = tid >> 5;               // 0..7
    int c0 = cg * 4;
    int row0 = blockIdx.x * 64 + rg * 8;

    float acc[8][4] = {};

    #pragma unroll
    for (int m = 0; m < 2; ++m) {
        const float* W = (m == 0) ? Wl : Wr;
        const float* A = (m == 0) ? agg : x;
        for (int kc = 0; kc < DD; kc += KC) {
            __syncthreads();
            {
                const float4* W4 = (const float4*)(W + (size_t)kc * DD);
                float4* s4 = (float4*)&sW[0][0];
                #pragma unroll
                for (int i = 0; i < 4; ++i) s4[tid + 256 * i] = W4[tid + 256 * i];
            }
            __syncthreads();
            for (int k = 0; k < KC; k += 4) {
                float4 a[8];
                #pragma unroll
                for (int r = 0; r < 8; ++r) {
                    int row = row0 + r;
                    if (row >= NN) row = NN - 1;
                    a[r] = *(const float4*)&A[(size_t)row * DD + kc + k];
                }
                #pragma unroll
                for (int kk = 0; kk < 4; ++kk) {
                    float4 w = *(const float4*)&sW[k + kk][c0];
                    #pragma unroll
                    for (int r = 0; r < 8; ++r) {
                        float av = (&a[r].x)[kk];
                        acc[r][0] += av * w.x;
                        acc[r][1] += av * w.y;
                        acc[r][2] += av * w.z;
                        acc[r][3] += av * w.w;
                    }
                }
            }
        }
    }

    // epilogue: bias, store x_raw, per-thread column stats
    float4 b4 = *(const float4*)&bl[c0];
    float s0 = 0, s1 = 0, s2 = 0, s3 = 0;
    float q0 = 0, q1 = 0, q2 = 0, q3 = 0;
    #pragma unroll
    for (int r = 0; r < 8; ++r) {
        int row = row0 + r;
        if (row < NN) {
            float4 o;
            o.x = acc[r][0] + b4.x;
            o.y = acc[r][1] + b4.y;
            o.z = acc[r][2] + b4.z;
            o.w = acc[r][3] + b4.w;
            *(float4*)&out_raw[(size_t)row * DD + c0] = o;
            s0 += o.x; q0 += o.x * o.x;
            s1 += o.y; q1 += o.y * o.y;
            s2 += o.z; q2 += o.z * o.z;
            s3 += o.w; q3 += o.w * o.w;
        }
    }

    // block-level column reduce in LDS (reuse sW: 2*8*128 floats <= 4096)
    __syncthreads();
    float* sp = &sW[0][0];         // [8][128]
    float* qp = sp + 1024;         // [8][128]
    *(float4*)&sp[rg * 128 + c0] = make_float4(s0, s1, s2, s3);
    *(float4*)&qp[rg * 128 + c0] = make_float4(q0, q1, q2, q3);
    __syncthreads();
    if (tid < 128) {
        float ts = 0, tq = 0;
        #pragma unroll
        for (int g = 0; g < 8; ++g) {
            ts += sp[g * 128 + tid];
            tq += qp[g * 128 + tid];
        }
        atomicAdd(&bn_sum[tid], ts);
        atomicAdd(&bn_sq[tid], tq);
    }
}

__global__ __launch_bounds__(256) void k_norm(const float* __restrict__ raw,
                                              const float* __restrict__ bn_sum,
                                              const float* __restrict__ bn_sq,
                                              const float* __restrict__ gamma,
                                              const float* __restrict__ beta,
                                              float* __restrict__ out) {
    const float invN = 1.0f / (float)NN;
    int total = NN * DD / 4;
    for (int idx = blockIdx.x * 256 + threadIdx.x; idx < total; idx += gridDim.x * 256) {
        int cp = idx & 31;
        float4 v = ((const float4*)raw)[idx];
        float4 s = ((const float4*)bn_sum)[cp];
        float4 q = ((const float4*)bn_sq)[cp];
        float4 g = ((const float4*)gamma)[cp];
        float4 b = ((const float4*)beta)[cp];
        float4 o;
        { float mu = s.x * invN; float var = q.x * invN - mu * mu;
          o.x = (v.x - mu) * rsqrtf(var + BN_EPS) * g.x + b.x; }
        { float mu = s.y * invN; float var = q.y * invN - mu * mu;
          o.y = (v.y - mu) * rsqrtf(var + BN_EPS) * g.y + b.y; }
        { float mu = s.z * invN; float var = q.z * invN - mu * mu;
          o.z = (v.z - mu) * rsqrtf(var + BN_EPS) * g.z + b.z; }
        { float mu = s.w * invN; float var = q.w * invN - mu * mu;
          o.w = (v.w - mu) * rsqrtf(var + BN_EPS) * g.w + b.w; }
        ((float4*)out)[idx] = o;
    }
}

extern "C" void kernel_launch(void* const* d_in, const int* in_sizes, int n_in,
                              void* d_out, int out_size, void* d_ws, size_t ws_size,
                              hipStream_t stream) {
    const float* x     = (const float*)d_in[0];
    const int*   ei    = (const int*)d_in[1];
    const float* Wl    = (const float*)d_in[2];
    const float* bl    = (const float*)d_in[3];
    const float* Wr    = (const float*)d_in[4];
    const float* gamma = (const float*)d_in[5];
    const float* beta  = (const float*)d_in[6];

    float* out_raw = (float*)d_out;                 // [NN][DD] x_raw
    float* out_bn  = out_raw + (size_t)NN * DD;     // [NN][DD] x_deskewed (temp agg)
    unsigned* bin  = (unsigned*)d_out;              // uint[NE], dead before k_gemm
    unsigned* xb   = (unsigned*)d_out + NE;         // uint[NN*64] bf16 copy, dead before k_gemm

    char* ws = (char*)d_ws;
    int*   cnt    = (int*)(ws + WS_CNT);
    int*   coff   = (int*)(ws + WS_COFF);
    int*   cur    = (int*)(ws + WS_CUR);
    int*   flag   = (int*)(ws + WS_FLAG);
    float* bn_sum = (float*)(ws + WS_BNSUM);
    float* bn_sq  = (float*)(ws + WS_BNSQ);
    int*   deg    = (int*)(ws + WS_DEG);
    int*   off    = (int*)(ws + WS_OFF);
    int*   csr    = (int*)(ws + WS_CSR);

    hipMemsetAsync(d_ws, 0, WS_ZERO, stream);

    k_detect<<<1, 64, 0, stream>>>(ei, flag);
    k_tobf16<<<2048, 256, 0, stream>>>(x, xb);
    k_bcount<<<512, 256, 0, stream>>>(ei, flag, cnt);
    k_scan<<<1, 256, 0, stream>>>(cnt, coff, cur);
    k_bin<<<(NE + RND - 1) / RND, 256, 0, stream>>>(ei, flag, cur, bin);
    k_csr<<<NB, 256, 0, stream>>>(bin, coff, csr, deg, off);
    k_agg<<<(NN * 64 + 255) / 256, 256, 0, stream>>>(xb, csr, deg, off, out_bn);
    k_gemm<<<(NN + 63) / 64, 256, 0, stream>>>(out_bn, x, Wl, Wr, bl, out_raw, bn_sum, bn_sq);
    k_norm<<<4096, 256, 0, stream>>>(out_raw, bn_sum, bn_sq, gamma, beta, out_bn);
}

// Round 7
// 312.479 us; speedup vs baseline: 9.6483x; 1.3211x over previous
//
#include <hip/hip_runtime.h>

constexpr int NN = 100000;
constexpr int NE = 3200000;
constexpr int DD = 128;
constexpr int NB = 782;          // ceil(NN/128) buckets of 128 nodes
constexpr int RND = 8192;        // edges binned per block (391 blocks)
#define BN_EPS 1e-5f

typedef __attribute__((ext_vector_type(8))) short bf16x8;
typedef __attribute__((ext_vector_type(4))) float f32x4;

// ---- workspace layout (bytes) ----
constexpr size_t WS_CNT   = 0;            // int[NB]
constexpr size_t WS_COFF  = 4096;         // int[NB+1]
constexpr size_t WS_CUR   = 8192;         // int[NB]
constexpr size_t WS_FLAG  = 12288;        // int[1]
constexpr size_t WS_BNSUM = 12800;        // float[128]
constexpr size_t WS_BNSQ  = 13312;        // float[128]
constexpr size_t WS_ZERO  = 16384;        // memset range
constexpr size_t WS_DEG   = 16384;        // int[NN]
constexpr size_t WS_OFF   = 416384;       // int[NN]
constexpr size_t WS_CSR   = 816384;       // int[NE]
constexpr size_t WS_WT    = 13616384;     // ushort[128*256] transposed bf16 W (64KB)
// d_out second half (out_bn, 51.2MB) hosts temporaries before k_norm writes it:
//   [0,12.8M):  bin  (uint[NE])   -- k_bin..k_csr
//   [0,25.6M):  aggb (bf16[NN*128]) -- k_agg..k_gemm (overwrites bin after k_csr)
//   [25.6M,51.2M): xb (bf16[NN*128]) -- k_tobf16..k_gemm

__device__ inline unsigned bf16rne(float f) {
    unsigned u = __float_as_uint(f);
    return (u + 0x7fffu + ((u >> 16) & 1u)) >> 16;
}

// Detect whether edge_index arrived as int64 (odd int32 words all zero).
__global__ void k_detect(const int* __restrict__ ei, int* __restrict__ flag) {
    int lane = threadIdx.x;
    int v = ei[2 * lane + 1];
    unsigned long long b = __ballot(v == 0);
    if (lane == 0) *flag = (b == ~0ull) ? 1 : 0;
}

// Pack x (fp32) into bf16 pairs: xb[i] = (bf16(x[2i+1])<<16) | bf16(x[2i]).
__global__ __launch_bounds__(256) void k_tobf16(const float* __restrict__ x,
                                                unsigned* __restrict__ xb) {
    int total = NN * DD / 4;
    for (int i = blockIdx.x * 256 + threadIdx.x; i < total; i += gridDim.x * 256) {
        float4 v = ((const float4*)x)[i];
        unsigned a = (bf16rne(v.y) << 16) | bf16rne(v.x);
        unsigned b = (bf16rne(v.w) << 16) | bf16rne(v.z);
        ((uint2*)xb)[i] = make_uint2(a, b);
    }
}

// Transposed bf16 weights: Wt[n][k] (k<128 -> Wl[k][n], else Wr[k-128][n]).
__global__ __launch_bounds__(256) void k_prepw(const float* __restrict__ Wl,
                                               const float* __restrict__ Wr,
                                               unsigned short* __restrict__ Wt) {
    int idx = blockIdx.x * 256 + threadIdx.x;   // 32768 total
    int n = idx >> 8, k = idx & 255;
    float v = (k < 128) ? Wl[(size_t)k * DD + n] : Wr[(size_t)(k - 128) * DD + n];
    Wt[idx] = (unsigned short)bf16rne(v);
}

// Coarse bucket histogram (782 buckets) via block-LDS hist + one flush.
__global__ __launch_bounds__(256) void k_bcount(const int* __restrict__ ei,
                                                const int* __restrict__ flag,
                                                int* __restrict__ cnt) {
    __shared__ int hist[NB];
    for (int i = threadIdx.x; i < NB; i += 256) hist[i] = 0;
    __syncthreads();
    int i64 = *flag;
    int stride = gridDim.x * 256;
    for (int e = blockIdx.x * 256 + threadIdx.x; e < NE; e += stride) {
        int dst = i64 ? ei[2 * (NE + e)] : ei[NE + e];
        atomicAdd(&hist[dst >> 7], 1);
    }
    __syncthreads();
    for (int i = threadIdx.x; i < NB; i += 256) {
        int c = hist[i];
        if (c) atomicAdd(&cnt[i], c);
    }
}

// Exclusive scan of the 782 bucket counts.
__global__ __launch_bounds__(256) void k_scan(const int* __restrict__ cnt,
                                              int* __restrict__ coff,
                                              int* __restrict__ cur) {
    __shared__ int s[NB];
    for (int i = threadIdx.x; i < NB; i += 256) s[i] = cnt[i];
    __syncthreads();
    if (threadIdx.x == 0) {
        int acc = 0;
        for (int i = 0; i < NB; ++i) { int c = s[i]; s[i] = acc; acc += c; }
    }
    __syncthreads();
    for (int i = threadIdx.x; i < NB; i += 256) { coff[i] = s[i]; cur[i] = s[i]; }
    if (threadIdx.x == 0) coff[NB] = NE;
}

// Bin edges by coarse bucket with per-block batched cursor reservation.
__global__ __launch_bounds__(256) void k_bin(const int* __restrict__ ei,
                                             const int* __restrict__ flag,
                                             int* __restrict__ cur,
                                             unsigned* __restrict__ bin) {
    __shared__ int hist[NB];
    __shared__ int base[NB];
    __shared__ int rk[NB];
    int tid = threadIdx.x;
    for (int i = tid; i < NB; i += 256) { hist[i] = 0; rk[i] = 0; }
    __syncthreads();
    int i64 = *flag;
    int e0 = blockIdx.x * RND;
    for (int j = tid; j < RND; j += 256) {
        int e = e0 + j;
        if (e < NE) {
            int dst = i64 ? ei[2 * (NE + e)] : ei[NE + e];
            atomicAdd(&hist[dst >> 7], 1);
        }
    }
    __syncthreads();
    for (int b = tid; b < NB; b += 256) {
        int c = hist[b];
        if (c > 0) base[b] = atomicAdd(&cur[b], c);
    }
    __syncthreads();
    for (int j = tid; j < RND; j += 256) {
        int e = e0 + j;
        if (e < NE) {
            int src = i64 ? ei[2 * e] : ei[e];
            int dst = i64 ? ei[2 * (NE + e)] : ei[NE + e];
            int b = dst >> 7;
            int r = atomicAdd(&rk[b], 1);
            bin[base[b] + r] = ((unsigned)src << 7) | (unsigned)(dst & 127);
        }
    }
}

// Per-bucket counting sort -> node-grouped CSR + deg/off.
__global__ __launch_bounds__(256) void k_csr(const unsigned* __restrict__ bin,
                                             const int* __restrict__ coff,
                                             int* __restrict__ csr,
                                             int* __restrict__ deg,
                                             int* __restrict__ off) {
    __shared__ int hist[128];
    __shared__ int sb[128];
    __shared__ int curs[128];
    int b = blockIdx.x;
    int tid = threadIdx.x;
    if (tid < 128) hist[tid] = 0;
    __syncthreads();
    int e0 = coff[b], e1 = coff[b + 1];
    for (int j = e0 + tid; j < e1; j += 256)
        atomicAdd(&hist[bin[j] & 127], 1);
    __syncthreads();
    if (tid == 0) {
        int acc = 0;
        for (int i = 0; i < 128; ++i) { sb[i] = acc; acc += hist[i]; }
    }
    __syncthreads();
    if (tid < 128) curs[tid] = sb[tid];
    __syncthreads();
    for (int j = e0 + tid; j < e1; j += 256) {
        unsigned p = bin[j];
        int d = p & 127;
        int r = atomicAdd(&curs[d], 1);
        csr[e0 + r] = (int)(p >> 7);
    }
    int n = b * 128 + tid;
    if (tid < 128 && n < NN) {
        deg[n] = hist[tid];
        off[n] = e0 + sb[tid];
    }
}

// Wave-per-node gather-sum from bf16 x copy; emits packed bf16 agg.
__global__ __launch_bounds__(256) void k_agg(const unsigned* __restrict__ xb,
                                             const int* __restrict__ csr,
                                             const int* __restrict__ deg,
                                             const int* __restrict__ off,
                                             unsigned* __restrict__ aggb) {
    int w = (blockIdx.x * 256 + threadIdx.x) >> 6;
    int lane = threadIdx.x & 63;
    if (w >= NN) return;
    int dg = deg[w];
    int o = off[w];
    float ax = 0.f, ay = 0.f;
    int j = 0;
    for (; j + 4 <= dg; j += 4) {
        int s0 = csr[o + j];
        int s1 = csr[o + j + 1];
        int s2 = csr[o + j + 2];
        int s3 = csr[o + j + 3];
        unsigned u0 = xb[(size_t)s0 * 64 + lane];
        unsigned u1 = xb[(size_t)s1 * 64 + lane];
        unsigned u2 = xb[(size_t)s2 * 64 + lane];
        unsigned u3 = xb[(size_t)s3 * 64 + lane];
        ax += (__uint_as_float(u0 << 16) + __uint_as_float(u1 << 16)) +
              (__uint_as_float(u2 << 16) + __uint_as_float(u3 << 16));
        ay += (__uint_as_float(u0 & 0xffff0000u) + __uint_as_float(u1 & 0xffff0000u)) +
              (__uint_as_float(u2 & 0xffff0000u) + __uint_as_float(u3 & 0xffff0000u));
    }
    for (; j < dg; ++j) {
        int s = csr[o + j];
        unsigned u = xb[(size_t)s * 64 + lane];
        ax += __uint_as_float(u << 16);
        ay += __uint_as_float(u & 0xffff0000u);
    }
    float inv = 1.0f / fmaxf((float)dg, 1.0f);
    unsigned lo = bf16rne(ax * inv);
    unsigned hi = bf16rne(ay * inv);
    aggb[(size_t)w * 64 + lane] = (hi << 16) | lo;
}

// MFMA GEMM: x_raw = [agg | x]_bf16 @ Wt^T + b, BN stats fused.
// Block: 4 waves; wave: 32 rows x 128 cols = 2x8 tiles of 16x16, K=256 in 8 steps.
__global__ __launch_bounds__(256) void k_gemm(const unsigned short* __restrict__ aggb,
                                              const unsigned short* __restrict__ xb,
                                              const unsigned short* __restrict__ Wt,
                                              const float* __restrict__ bl,
                                              float* __restrict__ out_raw,
                                              float* __restrict__ bn_sum,
                                              float* __restrict__ bn_sq) {
    __shared__ float s_s[4][128];
    __shared__ float s_q[4][128];
    int tid = threadIdx.x;
    int wv = tid >> 6, lane = tid & 63;
    int l15 = lane & 15, lhi = lane >> 4;
    int mr = blockIdx.x * 128 + wv * 32;

    int r0 = mr + l15;       if (r0 > NN - 1) r0 = NN - 1;
    int r1 = mr + 16 + l15;  if (r1 > NN - 1) r1 = NN - 1;
    const unsigned short* a0p = aggb + (size_t)r0 * DD;
    const unsigned short* a1p = aggb + (size_t)r1 * DD;
    const unsigned short* x0p = xb + (size_t)r0 * DD;
    const unsigned short* x1p = xb + (size_t)r1 * DD;

    f32x4 acc[2][8];
    #pragma unroll
    for (int m = 0; m < 2; ++m)
        #pragma unroll
        for (int nt = 0; nt < 8; ++nt)
            acc[m][nt] = (f32x4){0.f, 0.f, 0.f, 0.f};

    #pragma unroll
    for (int ks = 0; ks < 8; ++ks) {
        int kk = (ks & 3) * 32 + lhi * 8;
        bf16x8 a0, a1;
        if (ks < 4) {
            a0 = *(const bf16x8*)(a0p + kk);
            a1 = *(const bf16x8*)(a1p + kk);
        } else {
            a0 = *(const bf16x8*)(x0p + kk);
            a1 = *(const bf16x8*)(x1p + kk);
        }
        #pragma unroll
        for (int nt = 0; nt < 8; ++nt) {
            bf16x8 b = *(const bf16x8*)(Wt + (size_t)(nt * 16 + l15) * 256 + ks * 32 + lhi * 8);
            acc[0][nt] = __builtin_amdgcn_mfma_f32_16x16x32_bf16(a0, b, acc[0][nt], 0, 0, 0);
            acc[1][nt] = __builtin_amdgcn_mfma_f32_16x16x32_bf16(a1, b, acc[1][nt], 0, 0, 0);
        }
    }

    // epilogue: bias + store (D layout: row=lhi*4+reg, col=l15) + column stats
    float bias8[8];
    #pragma unroll
    for (int nt = 0; nt < 8; ++nt) bias8[nt] = bl[nt * 16 + l15];

    float s8[8] = {}, q8[8] = {};
    #pragma unroll
    for (int m = 0; m < 2; ++m) {
        #pragma unroll
        for (int r = 0; r < 4; ++r) {
            int row = mr + m * 16 + lhi * 4 + r;
            if (row < NN) {
                #pragma unroll
                for (int nt = 0; nt < 8; ++nt) {
                    float v = acc[m][nt][r] + bias8[nt];
                    out_raw[(size_t)row * DD + nt * 16 + l15] = v;
                    s8[nt] += v;
                    q8[nt] += v * v;
                }
            }
        }
    }

    // reduce across the 4 lane-groups sharing a column (lane^16, lane^32)
    #pragma unroll
    for (int nt = 0; nt < 8; ++nt) {
        s8[nt] += __shfl_xor(s8[nt], 16);
        s8[nt] += __shfl_xor(s8[nt], 32);
        q8[nt] += __shfl_xor(q8[nt], 16);
        q8[nt] += __shfl_xor(q8[nt], 32);
    }
    if (lhi == 0) {
        #pragma unroll
        for (int nt = 0; nt < 8; ++nt) {
            s_s[wv][nt * 16 + l15] = s8[nt];
            s_q[wv][nt * 16 + l15] = q8[nt];
        }
    }
    __syncthreads();
    if (tid < 128) {
        float ts = s_s[0][tid] + s_s[1][tid] + s_s[2][tid] + s_s[3][tid];
        float tq = s_q[0][tid] + s_q[1][tid] + s_q[2][tid] + s_q[3][tid];
        atomicAdd(&bn_sum[tid], ts);
        atomicAdd(&bn_sq[tid], tq);
    }
}

__global__ __launch_bounds__(256) void k_norm(const float* __restrict__ raw,
                                              const float* __restrict__ bn_sum,
                                              const float* __restrict__ bn_sq,
                                              const float* __restrict__ gamma,
                                              const float* __restrict__ beta,
                                              float* __restrict__ out) {
    const float invN = 1.0f / (float)NN;
    int total = NN * DD / 4;
    for (int idx = blockIdx.x * 256 + threadIdx.x; idx < total; idx += gridDim.x * 256) {
        int cp = idx & 31;
        float4 v = ((const float4*)raw)[idx];
        float4 s = ((const float4*)bn_sum)[cp];
        float4 q = ((const float4*)bn_sq)[cp];
        float4 g = ((const float4*)gamma)[cp];
        float4 b = ((const float4*)beta)[cp];
        float4 o;
        { float mu = s.x * invN; float var = q.x * invN - mu * mu;
          o.x = (v.x - mu) * rsqrtf(var + BN_EPS) * g.x + b.x; }
        { float mu = s.y * invN; float var = q.y * invN - mu * mu;
          o.y = (v.y - mu) * rsqrtf(var + BN_EPS) * g.y + b.y; }
        { float mu = s.z * invN; float var = q.z * invN - mu * mu;
          o.z = (v.z - mu) * rsqrtf(var + BN_EPS) * g.z + b.z; }
        { float mu = s.w * invN; float var = q.w * invN - mu * mu;
          o.w = (v.w - mu) * rsqrtf(var + BN_EPS) * g.w + b.w; }
        ((float4*)out)[idx] = o;
    }
}

extern "C" void kernel_launch(void* const* d_in, const int* in_sizes, int n_in,
                              void* d_out, int out_size, void* d_ws, size_t ws_size,
                              hipStream_t stream) {
    const float* x     = (const float*)d_in[0];
    const int*   ei    = (const int*)d_in[1];
    const float* Wl    = (const float*)d_in[2];
    const float* bl    = (const float*)d_in[3];
    const float* Wr    = (const float*)d_in[4];
    const float* gamma = (const float*)d_in[5];
    const float* beta  = (const float*)d_in[6];

    float* out_raw = (float*)d_out;                       // [NN][DD] x_raw
    float* out_bn  = out_raw + (size_t)NN * DD;           // [NN][DD] x_deskewed
    // temporaries inside the out_bn half (all dead before k_norm):
    unsigned*       bin  = (unsigned*)out_bn;                               // uint[NE]
    unsigned*       aggb = (unsigned*)out_bn;                               // bf16[NN*128] packed
    unsigned*       xb   = (unsigned*)((char*)out_bn + (size_t)NN * DD * 2);// bf16[NN*128] packed

    char* ws = (char*)d_ws;
    int*   cnt    = (int*)(ws + WS_CNT);
    int*   coff   = (int*)(ws + WS_COFF);
    int*   cur    = (int*)(ws + WS_CUR);
    int*   flag   = (int*)(ws + WS_FLAG);
    float* bn_sum = (float*)(ws + WS_BNSUM);
    float* bn_sq  = (float*)(ws + WS_BNSQ);
    int*   deg    = (int*)(ws + WS_DEG);
    int*   off    = (int*)(ws + WS_OFF);
    int*   csr    = (int*)(ws + WS_CSR);
    unsigned short* Wt = (unsigned short*)(ws + WS_WT);

    hipMemsetAsync(d_ws, 0, WS_ZERO, stream);

    k_detect<<<1, 64, 0, stream>>>(ei, flag);
    k_tobf16<<<2048, 256, 0, stream>>>(x, xb);
    k_prepw<<<128, 256, 0, stream>>>(Wl, Wr, Wt);
    k_bcount<<<512, 256, 0, stream>>>(ei, flag, cnt);
    k_scan<<<1, 256, 0, stream>>>(cnt, coff, cur);
    k_bin<<<(NE + RND - 1) / RND, 256, 0, stream>>>(ei, flag, cur, bin);
    k_csr<<<NB, 256, 0, stream>>>(bin, coff, csr, deg, off);
    k_agg<<<(NN * 64 + 255) / 256, 256, 0, stream>>>(xb, csr, deg, off, aggb);
    k_gemm<<<NB, 256, 0, stream>>>((const unsigned short*)aggb, (const unsigned short*)xb,
                                   Wt, bl, out_raw, bn_sum, bn_sq);
    k_norm<<<4096, 256, 0, stream>>>(out_raw, bn_sum, bn_sq, gamma, beta, out_bn);
}